// Round 18
// baseline (122.601 us; speedup 1.0000x reference)
//
#include <hip/hip_runtime.h>
#include <hip/hip_bf16.h>

// Problem constants (fixed by reference)
#define BB  4
#define CC  64      // input channels
#define NN  4096    // W*H
#define CF  32      // f/g channels (CH/2)
#define CHN 64      // h channels

typedef __attribute__((ext_vector_type(8))) __bf16 bf16x8;
typedef __attribute__((ext_vector_type(4))) __bf16 bf16x4;
typedef __attribute__((ext_vector_type(4))) float floatx4;

// clamp to [-60,60]; also kills NaN (v_max/v_min return the non-NaN operand)
__device__ __forceinline__ float clamp60(float v) {
    return fminf(fmaxf(v, -60.f), 60.f);
}
__device__ __forceinline__ float scrub(float v) {
    return fminf(fmaxf(v, -1e30f), 1e30f);
}

// sched_barrier mask 0x7F: ALU/SALU/MFMA/VMEM may cross, DS may NOT.
// Preserves the LDS write->read order (in-order DS pipe per wave) while
// letting next-chunk global loads hoist for cross-iteration pipelining.
#define DS_FENCE() __builtin_amdgcn_sched_barrier(0x7F)

// ---------------------------------------------------------------------------
// Kernel 1: 1x1 convs as MFMA GEMM (r14/r15/r17-verified, verbatim).
// ---------------------------------------------------------------------------
__global__ __launch_bounds__(256) void prep_kernel(
    const float* __restrict__ x, const float* __restrict__ y,
    const float* __restrict__ Wf, const float* __restrict__ bfp,
    const float* __restrict__ Wg, const float* __restrict__ bgp,
    const float* __restrict__ Wh, const float* __restrict__ bhp,
    __bf16* __restrict__ fT, __bf16* __restrict__ gT, __bf16* __restrict__ hvb)
{
    __shared__ __align__(16) __bf16 wbf[128][72];
    __shared__ float sbias[128];

    const int t  = threadIdx.x;
    const int w  = t >> 6;
    const int l  = t & 63;
    const int lo = l & 15;
    const int q  = l >> 4;

    const int b   = blockIdx.x >> 6;
    const int nb  = blockIdx.x & 63;
    const int nn  = nb * 64 + w * 16 + lo;

    for (int i = t; i < 128 * CC; i += 256) {
        int row = i >> 6, c = i & 63;
        float wv;
        if (row < 32)      wv = Wf[(size_t)row * CC + c];
        else if (row < 64) wv = Wg[(size_t)(row - 32) * CC + c];
        else               wv = Wh[(size_t)(row - 64) * CC + c];
        wbf[row][c] = (__bf16)wv;
    }
    if (t < 128) {
        if (t < 32)      sbias[t] = bfp[t];
        else if (t < 64) sbias[t] = bgp[t - 32];
        else             sbias[t] = bhp[t - 64];
    }
    __syncthreads();

    const float* xb = x + (size_t)b * CC * NN;
    const float* yb = y + (size_t)b * CC * NN;
    bf16x8 bx[2], by[2];
    #pragma unroll
    for (int kh = 0; kh < 2; kh++) {
        #pragma unroll
        for (int j = 0; j < 8; j++) {
            int c = kh * 32 + q * 8 + j;
            bx[kh][j] = (__bf16)xb[(size_t)c * NN + nn];
            by[kh][j] = (__bf16)yb[(size_t)c * NN + nn];
        }
    }

    const floatx4 zero4 = {0.f, 0.f, 0.f, 0.f};
    #pragma unroll
    for (int ct = 0; ct < 8; ct++) {
        const bf16x8* src = (ct < 2) ? bx : by;
        floatx4 acc = zero4;
        #pragma unroll
        for (int kh = 0; kh < 2; kh++) {
            const bf16x8 a = *(const bf16x8*)&wbf[ct*16 + lo][kh*32 + q*8];
            acc = __builtin_amdgcn_mfma_f32_16x16x32_bf16(a, src[kh], acc, 0, 0, 0);
        }
        if (ct < 4) {
            bf16x4 pk;
            #pragma unroll
            for (int r = 0; r < 4; r++)
                pk[r] = (__bf16)(acc[r] + sbias[ct*16 + q*4 + r]);
            __bf16* dstbase = (ct < 2) ? fT : gT;
            int cho = (ct & 1) * 16;
            *(bf16x4*)&dstbase[((size_t)b * NN + nn) * CF + cho + q*4] = pk;
        } else {
            #pragma unroll
            for (int r = 0; r < 4; r++) {
                int ch = (ct - 4) * 16 + q*4 + r;
                hvb[((size_t)b * CHN + ch) * NN + nn] =
                    (__bf16)(acc[r] + sbias[64 + ch]);
            }
        }
    }
}

// ---------------------------------------------------------------------------
// Kernel 2: fused MFMA flash attention + merge + epilogue (r17 structure).
// Changes vs r17: (1) asm lgkmcnt fences -> sched_barrier(0x7F) (DS order
// kept, VMEM free to cross); (2) explicit 2-deep register prefetch (A/B
// fragment sets, loop unrolled x2) so chunk i+1 loads fly under chunk i.
// ---------------------------------------------------------------------------
__global__ __launch_bounds__(256) void attn_kernel(
    const __bf16* __restrict__ fT, const __bf16* __restrict__ gT,
    const __bf16* __restrict__ hvb,
    const float* __restrict__ x, const float* __restrict__ gamma_p,
    float* __restrict__ out)
{
    __shared__ __align__(16) __bf16 pbf[128][72];   // 4 waves x 32-row P regions
    __shared__ float osum[32][68];                  // merge buffer [m][ch]
    __shared__ float lsum[32];

    const int t  = threadIdx.x;
    const int w  = t >> 6;                // wave = n-parity
    const int l  = t & 63;
    const int lo = l & 15;
    const int q  = l >> 4;

    const int mg = blockIdx.x & 127;      // 32-row tile
    const int b  = blockIdx.x >> 7;
    const int m0 = mg * 32;

    const __bf16* fb = fT  + (size_t)b * NN * CF;
    const __bf16* gb = gT  + (size_t)b * NN * CF;
    const __bf16* hb = hvb + (size_t)b * CHN * NN;

    bf16x8 ag[2];
    #pragma unroll
    for (int mt = 0; mt < 2; mt++)
        ag[mt] = *(const bf16x8*)(gb + (size_t)(m0 + mt*16 + lo) * CF + q * 8);

    const floatx4 zero4 = {0.f, 0.f, 0.f, 0.f};
    floatx4 oacc[2][4];                   // [mt][ct]: m=mt*16+q*4+r, ch=ct*16+lo
    #pragma unroll
    for (int mt = 0; mt < 2; mt++)
        #pragma unroll
        for (int ct = 0; ct < 4; ct++) oacc[mt][ct] = zero4;
    float lrun[2][4];
    #pragma unroll
    for (int mt = 0; mt < 2; mt++)
        #pragma unroll
        for (int r = 0; r < 4; r++) lrun[mt][r] = 0.f;

    // fragment loader for chunk index ci (n0 = (4*ci + w)*64)
    #define LOAD_CHUNK(ci, bffX, bhhX)                                          \
        {                                                                       \
            const int n0_ = (4*(ci) + w) * 64;                                  \
            _Pragma("unroll")                                                   \
            for (int nt = 0; nt < 4; nt++)                                      \
                bffX[nt] = *(const bf16x8*)(fb + (size_t)(n0_ + nt*16 + lo) * CF + q * 8); \
            _Pragma("unroll")                                                   \
            for (int ct = 0; ct < 4; ct++)                                      \
                _Pragma("unroll")                                               \
                for (int jb = 0; jb < 2; jb++)                                  \
                    bhhX[ct][jb] = *(const bf16x8*)(hb + (size_t)(ct*16 + lo) * NN + n0_ + jb*32 + q*8); \
        }

    // compute for one chunk given fragments (r17-verbatim math)
    #define COMPUTE_CHUNK(bffX, bhhX)                                           \
        {                                                                       \
            _Pragma("unroll")                                                   \
            for (int mt = 0; mt < 2; mt++) {                                    \
                floatx4 s4[4];                                                  \
                _Pragma("unroll")                                               \
                for (int nt = 0; nt < 4; nt++)                                  \
                    s4[nt] = __builtin_amdgcn_mfma_f32_16x16x32_bf16(ag[mt], bffX[nt], zero4, 0, 0, 0); \
                _Pragma("unroll")                                               \
                for (int nt = 0; nt < 4; nt++)                                  \
                    _Pragma("unroll")                                           \
                    for (int r = 0; r < 4; r++) {                               \
                        float pv = __expf(clamp60(s4[nt][r]));                  \
                        s4[nt][r] = pv;                                         \
                        lrun[mt][r] += pv;                                      \
                    }                                                           \
                _Pragma("unroll")                                               \
                for (int nt = 0; nt < 4; nt++)                                  \
                    _Pragma("unroll")                                           \
                    for (int r = 0; r < 4; r++)                                 \
                        pbf[w*32 + mt*16 + q*4 + r][nt*16 + lo] = (__bf16)s4[nt][r]; \
            }                                                                   \
            DS_FENCE();                                                         \
            bf16x8 ap[2][2];                                                    \
            _Pragma("unroll")                                                   \
            for (int mt = 0; mt < 2; mt++)                                      \
                _Pragma("unroll")                                               \
                for (int jb = 0; jb < 2; jb++)                                  \
                    ap[mt][jb] = *(const bf16x8*)&pbf[w*32 + mt*16 + lo][jb*32 + q*8]; \
            DS_FENCE();                                                         \
            _Pragma("unroll")                                                   \
            for (int mt = 0; mt < 2; mt++)                                      \
                _Pragma("unroll")                                               \
                for (int ct = 0; ct < 4; ct++)                                  \
                    _Pragma("unroll")                                           \
                    for (int jb = 0; jb < 2; jb++)                              \
                        oacc[mt][ct] = __builtin_amdgcn_mfma_f32_16x16x32_bf16( \
                            ap[mt][jb], bhhX[ct][jb], oacc[mt][ct], 0, 0, 0);   \
        }

    bf16x8 bffA[4], bhhA[4][2], bffB[4], bhhB[4][2];
    LOAD_CHUNK(0, bffA, bhhA);
    for (int i = 0; i < 8; i++) {
        LOAD_CHUNK(2*i + 1, bffB, bhhB);      // prefetch odd chunk
        COMPUTE_CHUNK(bffA, bhhA);
        if (i < 7) LOAD_CHUNK(2*i + 2, bffA, bhhA);   // prefetch next even
        COMPUTE_CHUNK(bffB, bhhB);
    }
    #undef LOAD_CHUNK
    #undef COMPUTE_CHUNK

    // row-sum reduction across the 16 lanes sharing each row
    #pragma unroll
    for (int mt = 0; mt < 2; mt++)
        #pragma unroll
        for (int r = 0; r < 4; r++) {
            lrun[mt][r] += __shfl_xor(lrun[mt][r], 1, 64);
            lrun[mt][r] += __shfl_xor(lrun[mt][r], 2, 64);
            lrun[mt][r] += __shfl_xor(lrun[mt][r], 4, 64);
            lrun[mt][r] += __shfl_xor(lrun[mt][r], 8, 64);
        }

    // additive merge across the 4 parity waves (r17-verbatim)
    for (int ww = 0; ww < 4; ww++) {
        if (w == ww) {
            #pragma unroll
            for (int mt = 0; mt < 2; mt++) {
                #pragma unroll
                for (int ct = 0; ct < 4; ct++)
                    #pragma unroll
                    for (int r = 0; r < 4; r++) {
                        float* p = &osum[mt*16 + q*4 + r][ct*16 + lo];
                        *p = (ww == 0 ? 0.f : *p) + oacc[mt][ct][r];
                    }
                if (lo == 0)
                    #pragma unroll
                    for (int r = 0; r < 4; r++) {
                        float* p = &lsum[mt*16 + q*4 + r];
                        *p = (ww == 0 ? 0.f : *p) + lrun[mt][r];
                    }
            }
        }
        __syncthreads();
    }

    // fused epilogue (r17-verbatim)
    const float gam = gamma_p[0];
    #pragma unroll
    for (int it = 0; it < 8; it++) {
        int cell = it * 256 + t;
        int m  = cell & 31;
        int ch = cell >> 5;
        size_t gi = ((size_t)b * CHN + ch) * NN + m0 + m;
        float ov = scrub(osum[m][ch] / lsum[m]);
        out[gi] = gam * ov + x[gi];
    }
}

// ---------------------------------------------------------------------------
extern "C" void kernel_launch(void* const* d_in, const int* in_sizes, int n_in,
                              void* d_out, int out_size, void* d_ws, size_t ws_size,
                              hipStream_t stream)
{
    const float* x     = (const float*)d_in[0];
    const float* y     = (const float*)d_in[1];
    const float* Wf    = (const float*)d_in[2];
    const float* bf    = (const float*)d_in[3];
    const float* Wg    = (const float*)d_in[4];
    const float* bg    = (const float*)d_in[5];
    const float* Wh    = (const float*)d_in[6];
    const float* bh    = (const float*)d_in[7];
    const float* gamma = (const float*)d_in[8];
    float* out = (float*)d_out;

    __bf16* wsb = (__bf16*)d_ws;
    __bf16* fT  = wsb;                                // 1 MB
    __bf16* gT  = fT + (size_t)BB * NN * CF;          // 1 MB
    __bf16* hvb = gT + (size_t)BB * NN * CF;          // 2 MB
    // total 4 MB of ws

    prep_kernel<<<dim3(BB * 64), dim3(256), 0, stream>>>(
        x, y, Wf, bf, Wg, bg, Wh, bh, fT, gT, hvb);
    attn_kernel<<<dim3(BB * 128), dim3(256), 0, stream>>>(
        fT, gT, hvb, x, gamma, out);
}